// Round 9
// baseline (1271.745 us; speedup 1.0000x reference)
//
#include <hip/hip_runtime.h>
#include <hip/hip_fp16.h>
#include <math.h>

// Problem constants (match reference)
constexpr int NG  = 100000;          // graphs
constexpr int NPG = 38;              // nodes per graph
constexpr int NN  = NG * NPG;        // 3,800,000 nodes
constexpr long long NE = 60800000LL; // edges

// Binning
constexpr int BIN_SHIFT = 14;                     // 16384 nodes/bin
constexpr int BINW      = 1 << BIN_SHIFT;
constexpr int NB        = (NN + BINW - 1) / BINW; // 232 bins (src and dst)

// P1 sub-rounds (region reuse keeps ws small)
constexpr int NR    = 4;
constexpr int I4_R  = (int)(NE / 4 / NR);         // 3,800,000 int4 per sub-round
constexpr int NBLK1 = 1000;
constexpr int I4_B  = I4_R / NBLK1;               // 3800 int4 per block (exact)
constexpr int CHUNK = 4096;                       // records per sort chunk
constexpr int CH_I4 = CHUNK / 4;                  // 1024 int4 per chunk
constexpr int NW    = 8;                          // waves per 512-thread block

// Region capacities (fixed dataset; mean + >=10 sigma)
constexpr int CAPS1 = 68096;    // per src-bin, per sub-round
constexpr int CAPD  = 267264;   // per dst-bin, all edges
constexpr int NB2   = 4;        // P2 blocks per src-bin
constexpr int NSPLIT = 2;       // reduce splits per dst-bin

// Workspace layout (bytes)
constexpr size_t AGG_BYTES  = (size_t)NN * 4;                 // 15,200,000 (fallback path)
constexpr size_t XH_OFF     = AGG_BYTES;
constexpr size_t XH_BYTES   = (size_t)NB * BINW * 2;          // 7,602,176
constexpr size_t CUR1_OFF   = XH_OFF + XH_BYTES;
constexpr size_t CUR2_OFF   = CUR1_OFF + 1024;
constexpr size_t PSTRIDE    = (size_t)NB * BINW;              // 3,801,088 floats
constexpr size_t PART_OFF   = ((CUR2_OFF + 1024 + 255) / 256) * 256;
constexpr size_t PART_BYTES = (size_t)NSPLIT * PSTRIDE * 4;   // 30,408,704
constexpr size_t REG1_OFF   = PART_OFF + PART_BYTES;
constexpr size_t REG1_BYTES = (size_t)NB * CAPS1 * 8;         // 126,386,176
constexpr size_t REG2_OFF   = REG1_OFF + REG1_BYTES;
constexpr size_t REG2_BYTES = (size_t)NB * CAPD * 4;          // 248,020,992
constexpr size_t WS_NEEDED  = REG2_OFF + REG2_BYTES;          // ~407 MiB

// ---------------------------------------------------------------------------
// Ballot multi-split rank: within-wave rank for 8-bit bin keys + wave-private
// LDS histogram update (leader lane). No LDS atomics. All 64 lanes must call
// (inactive lanes pass bin=255).
// ---------------------------------------------------------------------------
__device__ __forceinline__ int multisplit_rank(int bin, int lane,
                                               volatile int* whrow)
{
    unsigned long long m = ~0ULL;
    #pragma unroll
    for (int bit = 0; bit < 8; ++bit) {
        const int bv = (bin >> bit) & 1;
        const unsigned long long bb = __ballot(bv != 0);
        m &= bv ? bb : ~bb;
    }
    const unsigned long long lower = (1ULL << lane) - 1ULL;
    const int lr  = __popcll(m & lower);
    const int cur = whrow[bin];
    if (lr == 0) whrow[bin] = cur + __popcll(m);
    return cur + lr;
}

// ---------------------------------------------------------------------------
// X cast: f32 -> fp16 copy
// ---------------------------------------------------------------------------
__global__ void __launch_bounds__(256) xcast_kernel(
    const float* __restrict__ x, __half2* __restrict__ xh2)
{
    const int i = blockIdx.x * 256 + threadIdx.x;    // over NN/4
    if (i < NN / 4) {
        float4 v = ((const float4*)x)[i];
        xh2[2 * i + 0] = __floats2half2_rn(v.x, v.y);
        xh2[2 * i + 1] = __floats2half2_rn(v.z, v.w);
    }
}

// ---------------------------------------------------------------------------
// P1: partition edges by SRC-bin. Record u64 = [srclow14 | dst22 | fp16(ea*w+b)].
// LDS counting sort per 4096-record chunk; ranks via ballot multi-split
// (no LDS atomics); dynamic run allocation on cur1 (232 global atomics/chunk).
// ---------------------------------------------------------------------------
__global__ void __launch_bounds__(512) p1_kernel(
    const int*   __restrict__ ei,
    const float* __restrict__ ea,
    const float* __restrict__ wptr,
    const float* __restrict__ bptr,
    unsigned long long* __restrict__ reg1,
    int* __restrict__ cur1,
    int roff)                          // int4 offset of this sub-round
{
    __shared__ unsigned long long sbuf[CHUNK];   // 32 KB
    __shared__ unsigned char     sbin[CHUNK];    // 4 KB
    __shared__ int whist[NW][256];               // 8 KB wave-private histograms
    __shared__ int s_scan[256];                  // 1 KB
    __shared__ int gofs[NB];

    const int t    = threadIdx.x;
    const int lane = t & 63;
    const int wv   = t >> 6;
    volatile int* whrow = &whist[wv][0];

    for (int i = lane; i < 256; i += 64) whist[wv][i] = 0;   // wave-private init
    __syncthreads();

    const float w = wptr[0], b = bptr[0];
    const int4*   src4 = (const int4*)ei + roff + (size_t)blockIdx.x * I4_B;
    const int4*   dst4 = (const int4*)(ei + NE) + roff + (size_t)blockIdx.x * I4_B;
    const float4* ea4  = (const float4*)ea + roff + (size_t)blockIdx.x * I4_B;

    for (int c0 = 0; c0 < I4_B; c0 += CH_I4) {
        const int n4 = min(CH_I4, I4_B - c0);
        int rbin[8]; unsigned long long rpk[8]; int rrank[8];
        #pragma unroll
        for (int u = 0; u < 2; ++u) {
            const int j = u * 512 + t;
            const bool act = j < n4;
            int4   s4 = make_int4(0, 0, 0, 0);
            int4   d4 = make_int4(0, 0, 0, 0);
            float4 e4 = make_float4(0.f, 0.f, 0.f, 0.f);
            if (act) { s4 = src4[c0 + j]; d4 = dst4[c0 + j]; e4 = ea4[c0 + j]; }
            int   ss[4] = {s4.x, s4.y, s4.z, s4.w};
            int   dd[4] = {d4.x, d4.y, d4.z, d4.w};
            float ee[4] = {e4.x, e4.y, e4.z, e4.w};
            #pragma unroll
            for (int k = 0; k < 4; ++k) {
                const int idx = u * 4 + k;
                int bin = 255;
                unsigned long long pk = 0;
                if (act) {
                    bin = ss[k] >> BIN_SHIFT;
                    __half_raw hr = __float2half_rn(ee[k] * w + b);
                    pk = ((unsigned long long)(unsigned)(ss[k] & (BINW - 1)) << 38)
                       | ((unsigned long long)(unsigned)dd[k] << 16)
                       | (unsigned long long)(unsigned short)hr.x;
                }
                rbin[idx]  = bin;
                rpk[idx]   = pk;
                rrank[idx] = multisplit_rank(bin, lane, whrow);   // uniform call
            }
        }
        __syncthreads();

        // combine: per-bin exclusive prefix over waves (in place) + bin totals
        if (t < 256) {
            int s = 0;
            #pragma unroll
            for (int wv2 = 0; wv2 < NW; ++wv2) {
                int c = whist[wv2][t]; whist[wv2][t] = s; s += c;
            }
            s_scan[t] = s;
        }
        __syncthreads();

        // inclusive Hillis-Steele scan over 256 bin totals
        int acc = 0;
        if (t < 256) acc = s_scan[t];
        for (int off = 1; off < 256; off <<= 1) {
            int tmp = 0;
            if (t < 256 && t >= off) tmp = s_scan[t - off];
            __syncthreads();
            if (t < 256) { acc += tmp; s_scan[t] = acc; }
            __syncthreads();
        }

        // allocate run offsets in global regions (bins >= NB are dummies)
        if (t < NB) {
            const int excl = (t == 0) ? 0 : s_scan[t - 1];
            const int rl   = s_scan[t] - excl;
            gofs[t] = (rl > 0) ? atomicAdd(&cur1[t], rl) : 0;
        }
        // scatter into sorted LDS buffer
        #pragma unroll
        for (int k = 0; k < 8; ++k) {
            if (rbin[k] < NB) {
                const int excl = (rbin[k] == 0) ? 0 : s_scan[rbin[k] - 1];
                const int idx  = excl + whist[wv][rbin[k]] + rrank[k];
                sbuf[idx] = rpk[k];
                sbin[idx] = (unsigned char)rbin[k];
            }
        }
        __syncthreads();

        // coalesced run write-out (real records only; dummies sort after)
        const int tot = s_scan[NB - 1];
        for (int k = t; k < tot; k += 512) {
            const unsigned long long r = sbuf[k];
            const int bin  = sbin[k];
            const int excl = (bin == 0) ? 0 : s_scan[bin - 1];
            reg1[(size_t)bin * CAPS1 + gofs[bin] + (k - excl)] = r;
        }
        __syncthreads();

        for (int i = lane; i < 256; i += 64) whist[wv][i] = 0;  // wave-private reset
    }
}

// ---------------------------------------------------------------------------
// P2: per src-bin, xh slice in LDS; msg = xh_lds[srclow] * m; partition by
// DST-bin into 4B records [dstlow14<<16 | fp16(msg)]. Ballot multi-split
// ranks; dynamic alloc on cur2.
// ---------------------------------------------------------------------------
__global__ void __launch_bounds__(512) p2_kernel(
    const __half* __restrict__ xh,
    const unsigned long long* __restrict__ reg1,
    const int* __restrict__ cur1,
    unsigned int* __restrict__ reg2,
    int* __restrict__ cur2)
{
    __shared__ __half        xsl[BINW];    // 32 KB
    __shared__ unsigned int  sbuf[CHUNK];  // 16 KB
    __shared__ unsigned char sbin[CHUNK];  // 4 KB
    __shared__ int whist[NW][256];         // 8 KB
    __shared__ int s_scan[256];
    __shared__ int gofs[NB];

    const int t    = threadIdx.x;
    const int lane = t & 63;
    const int wv   = t >> 6;
    volatile int* whrow = &whist[wv][0];
    const int sb = blockIdx.x >> 2;        // NB2 = 4
    const int jb = blockIdx.x & 3;

    {   // stage xh slice (2048 uint4)
        const uint4* s = (const uint4*)(xh + (size_t)sb * BINW);
        uint4* d = (uint4*)xsl;
        for (int i = t; i < BINW / 8; i += 512) d[i] = s[i];
    }
    for (int i = lane; i < 256; i += 64) whist[wv][i] = 0;
    __syncthreads();

    const int n2    = cur1[sb];
    const int cpb   = (n2 + NB2 - 1) / NB2;
    const int start = jb * cpb;
    const int end   = min(start + cpb, n2);
    const unsigned long long* seg = reg1 + (size_t)sb * CAPS1;

    for (int c0 = start; c0 < end; c0 += CHUNK) {
        const int cnt = min(CHUNK, end - c0);
        int rbin[8]; unsigned int rpk[8]; int rrank[8];
        #pragma unroll
        for (int u = 0; u < 8; ++u) {
            const int j = u * 512 + t;
            int bin = 255; unsigned int pk = 0;
            if (j < cnt) {
                const unsigned long long r = seg[c0 + j];
                const int srclow        = (int)(r >> 38);
                const unsigned int dst  = (unsigned int)(r >> 16) & 0x3FFFFFu;
                __half_raw hm; hm.x = (unsigned short)(r & 0xFFFFu);
                const float msg = __half2float(xsl[srclow]) * __half2float(__half(hm));
                __half_raw ho = __float2half_rn(msg);
                bin = (int)(dst >> BIN_SHIFT);
                pk  = ((dst & (unsigned)(BINW - 1)) << 16) | (unsigned int)(unsigned short)ho.x;
            }
            rbin[u]  = bin;
            rpk[u]   = pk;
            rrank[u] = multisplit_rank(bin, lane, whrow);   // uniform call
        }
        __syncthreads();

        if (t < 256) {
            int s = 0;
            #pragma unroll
            for (int wv2 = 0; wv2 < NW; ++wv2) {
                int c = whist[wv2][t]; whist[wv2][t] = s; s += c;
            }
            s_scan[t] = s;
        }
        __syncthreads();

        int acc = 0;
        if (t < 256) acc = s_scan[t];
        for (int off = 1; off < 256; off <<= 1) {
            int tmp = 0;
            if (t < 256 && t >= off) tmp = s_scan[t - off];
            __syncthreads();
            if (t < 256) { acc += tmp; s_scan[t] = acc; }
            __syncthreads();
        }

        if (t < NB) {
            const int excl = (t == 0) ? 0 : s_scan[t - 1];
            const int rl   = s_scan[t] - excl;
            gofs[t] = (rl > 0) ? atomicAdd(&cur2[t], rl) : 0;
        }
        #pragma unroll
        for (int u = 0; u < 8; ++u) {
            if (rbin[u] < NB) {
                const int excl = (rbin[u] == 0) ? 0 : s_scan[rbin[u] - 1];
                const int idx  = excl + whist[wv][rbin[u]] + rrank[u];
                sbuf[idx] = rpk[u];
                sbin[idx] = (unsigned char)rbin[u];
            }
        }
        __syncthreads();

        const int tot = s_scan[NB - 1];
        for (int k = t; k < tot; k += 512) {
            const unsigned int r = sbuf[k];
            const int bin  = sbin[k];
            const int excl = (bin == 0) ? 0 : s_scan[bin - 1];
            reg2[(size_t)bin * CAPD + gofs[bin] + (k - excl)] = r;
        }
        __syncthreads();

        for (int i = lane; i < 256; i += 64) whist[wv][i] = 0;
    }
}

// ---------------------------------------------------------------------------
// P3: split-2 per dst-bin LDS f32 atomic reduction (at the DS-atomic floor).
// ---------------------------------------------------------------------------
__global__ void __launch_bounds__(1024) reduce_kernel(
    const unsigned int* __restrict__ reg2,
    const int* __restrict__ cur2,
    float* __restrict__ part_agg)
{
    __shared__ float acc[BINW];      // 64 KB
    const int t    = threadIdx.x;
    const int b    = blockIdx.x >> 1;
    const int part = blockIdx.x & 1;
    for (int i = t; i < BINW; i += 1024) acc[i] = 0.0f;
    __syncthreads();

    const int n    = cur2[b];
    const int half = n >> 1;
    const int i0   = part ? half : 0;
    const int i1   = part ? n : half;
    const unsigned int* seg = reg2 + (size_t)b * CAPD;

    unsigned int a[8], nb[8];
    int k = i0 + t;
    if (k + 7168 < i1) {
        #pragma unroll
        for (int u = 0; u < 8; ++u) a[u] = seg[k + u * 1024];
        k += 8192;
        for (; k + 7168 < i1; k += 8192) {
            #pragma unroll
            for (int u = 0; u < 8; ++u) nb[u] = seg[k + u * 1024];
            #pragma unroll
            for (int u = 0; u < 8; ++u) {
                __half_raw h; h.x = (unsigned short)(a[u] & 0xFFFFu);
                atomicAdd(&acc[a[u] >> 16], __half2float(__half(h)));
            }
            #pragma unroll
            for (int u = 0; u < 8; ++u) a[u] = nb[u];
        }
        #pragma unroll
        for (int u = 0; u < 8; ++u) {
            __half_raw h; h.x = (unsigned short)(a[u] & 0xFFFFu);
            atomicAdd(&acc[a[u] >> 16], __half2float(__half(h)));
        }
    }
    for (; k < i1; k += 1024) {
        unsigned int r = seg[k];
        __half_raw h; h.x = (unsigned short)(r & 0xFFFFu);
        atomicAdd(&acc[r >> 16], __half2float(__half(h)));
    }
    __syncthreads();

    float* dst = part_agg + (size_t)part * PSTRIDE + ((size_t)b << BIN_SHIFT);
    for (int i = t; i < BINW; i += 1024) dst[i] = acc[i];
}

// ---------------------------------------------------------------------------
// Fallback single-pass edge kernel (used only if ws_size too small)
// ---------------------------------------------------------------------------
__global__ void __launch_bounds__(256) edge_kernel(
    const float* __restrict__ x,
    const int*   __restrict__ ei,
    const float* __restrict__ ea,
    const float* __restrict__ wptr,
    const float* __restrict__ bptr,
    float*       __restrict__ agg)
{
    const float w = wptr[0];
    const float b = bptr[0];
    const int nvec = (int)(NE / 4);
    const int4*   src4 = (const int4*)ei;
    const int4*   dst4 = (const int4*)(ei + NE);
    const float4* ea4  = (const float4*)ea;
    const int stride = gridDim.x * blockDim.x;
    for (int i = blockIdx.x * blockDim.x + threadIdx.x; i < nvec; i += stride) {
        int4   s = src4[i];
        int4   d = dst4[i];
        float4 e = ea4[i];
        atomicAdd(&agg[d.x], x[s.x] * (e.x * w + b));
        atomicAdd(&agg[d.y], x[s.y] * (e.y * w + b));
        atomicAdd(&agg[d.z], x[s.z] * (e.z * w + b));
        atomicAdd(&agg[d.w], x[s.w] * (e.w * w + b));
    }
}

// ---------------------------------------------------------------------------
// Head (main path): nodes = x*cr + (p0+p1) + cb, MLP 38->4->4->1, sigmoid*11
// ---------------------------------------------------------------------------
__global__ void __launch_bounds__(256) head_kernel2(
    const float* __restrict__ x,
    const float* __restrict__ p0,
    const float* __restrict__ p1,
    const float* __restrict__ conv_root,
    const float* __restrict__ conv_bias,
    const float* __restrict__ W1, const float* __restrict__ b1,
    const float* __restrict__ W2, const float* __restrict__ b2,
    const float* __restrict__ W3, const float* __restrict__ b3,
    float* __restrict__ out)
{
    __shared__ float nv[256 * NPG];
    const float cr = conv_root[0];
    const float cb = conv_bias[0];

    const int gbase = blockIdx.x * 256;
    const int gcount = (NG - gbase < 256) ? (NG - gbase) : 256;
    const int fcount = gcount * NPG;
    const long long nbase = (long long)gbase * NPG;

    for (int k = threadIdx.x; k < fcount; k += 256) {
        long long gi = nbase + k;
        nv[k] = x[gi] * cr + p0[gi] + p1[gi] + cb;
    }
    __syncthreads();

    const int g = gbase + threadIdx.x;
    if (g < NG) {
        const float* p = &nv[threadIdx.x * NPG];
        float h0 = b1[0], h1 = b1[1], h2 = b1[2], h3 = b1[3];
        #pragma unroll
        for (int j = 0; j < NPG; ++j) {
            float v = p[j];
            h0 += v * W1[j * 4 + 0];
            h1 += v * W1[j * 4 + 1];
            h2 += v * W1[j * 4 + 2];
            h3 += v * W1[j * 4 + 3];
        }
        h0 = fmaxf(h0, 0.f); h1 = fmaxf(h1, 0.f);
        h2 = fmaxf(h2, 0.f); h3 = fmaxf(h3, 0.f);

        float q0 = b2[0] + h0 * W2[0] + h1 * W2[4] + h2 * W2[8]  + h3 * W2[12];
        float q1 = b2[1] + h0 * W2[1] + h1 * W2[5] + h2 * W2[9]  + h3 * W2[13];
        float q2 = b2[2] + h0 * W2[2] + h1 * W2[6] + h2 * W2[10] + h3 * W2[14];
        float q3 = b2[3] + h0 * W2[3] + h1 * W2[7] + h2 * W2[11] + h3 * W2[15];
        q0 = fmaxf(q0, 0.f); q1 = fmaxf(q1, 0.f);
        q2 = fmaxf(q2, 0.f); q3 = fmaxf(q3, 0.f);

        float z = b3[0] + q0 * W3[0] + q1 * W3[1] + q2 * W3[2] + q3 * W3[3];
        float sgm = 1.0f / (1.0f + __expf(-z));
        out[g] = 11.0f * sgm;
    }
}

// ---------------------------------------------------------------------------
// Head (fallback path): reads agg
// ---------------------------------------------------------------------------
__global__ void __launch_bounds__(256) head_kernel(
    const float* __restrict__ x,
    const float* __restrict__ agg,
    const float* __restrict__ conv_root,
    const float* __restrict__ conv_bias,
    const float* __restrict__ W1, const float* __restrict__ b1,
    const float* __restrict__ W2, const float* __restrict__ b2,
    const float* __restrict__ W3, const float* __restrict__ b3,
    float* __restrict__ out)
{
    __shared__ float nv[256 * NPG];
    const float cr = conv_root[0];
    const float cb = conv_bias[0];

    const int gbase = blockIdx.x * 256;
    const int gcount = (NG - gbase < 256) ? (NG - gbase) : 256;
    const int fcount = gcount * NPG;
    const long long nbase = (long long)gbase * NPG;

    for (int k = threadIdx.x; k < fcount; k += 256) {
        long long gi = nbase + k;
        nv[k] = x[gi] * cr + agg[gi] + cb;
    }
    __syncthreads();

    const int g = gbase + threadIdx.x;
    if (g < NG) {
        const float* p = &nv[threadIdx.x * NPG];
        float h0 = b1[0], h1 = b1[1], h2 = b1[2], h3 = b1[3];
        #pragma unroll
        for (int j = 0; j < NPG; ++j) {
            float v = p[j];
            h0 += v * W1[j * 4 + 0];
            h1 += v * W1[j * 4 + 1];
            h2 += v * W1[j * 4 + 2];
            h3 += v * W1[j * 4 + 3];
        }
        h0 = fmaxf(h0, 0.f); h1 = fmaxf(h1, 0.f);
        h2 = fmaxf(h2, 0.f); h3 = fmaxf(h3, 0.f);

        float q0 = b2[0] + h0 * W2[0] + h1 * W2[4] + h2 * W2[8]  + h3 * W2[12];
        float q1 = b2[1] + h0 * W2[1] + h1 * W2[5] + h2 * W2[9]  + h3 * W2[13];
        float q2 = b2[2] + h0 * W2[2] + h1 * W2[6] + h2 * W2[10] + h3 * W2[14];
        float q3 = b2[3] + h0 * W2[3] + h1 * W2[7] + h2 * W2[11] + h3 * W2[15];
        q0 = fmaxf(q0, 0.f); q1 = fmaxf(q1, 0.f);
        q2 = fmaxf(q2, 0.f); q3 = fmaxf(q3, 0.f);

        float z = b3[0] + q0 * W3[0] + q1 * W3[1] + q2 * W3[2] + q3 * W3[3];
        float sgm = 1.0f / (1.0f + __expf(-z));
        out[g] = 11.0f * sgm;
    }
}

extern "C" void kernel_launch(void* const* d_in, const int* in_sizes, int n_in,
                              void* d_out, int out_size, void* d_ws, size_t ws_size,
                              hipStream_t stream) {
    const float* x         = (const float*)d_in[0];
    const int*   ei        = (const int*)  d_in[1];
    const float* ea        = (const float*)d_in[2];
    const float* conv_root = (const float*)d_in[3];
    const float* conv_bias = (const float*)d_in[4];
    const float* ew        = (const float*)d_in[5];
    const float* eb        = (const float*)d_in[6];
    const float* W1        = (const float*)d_in[7];
    const float* b1        = (const float*)d_in[8];
    const float* W2        = (const float*)d_in[9];
    const float* b2        = (const float*)d_in[10];
    const float* W3        = (const float*)d_in[11];
    const float* b3        = (const float*)d_in[12];

    char*  ws  = (char*)d_ws;
    float* agg = (float*)ws;
    float* out = (float*)d_out;

    if (ws_size >= WS_NEEDED) {
        __half*             xh    = (__half*)(ws + XH_OFF);
        int*                cur1  = (int*)(ws + CUR1_OFF);
        int*                cur2  = (int*)(ws + CUR2_OFF);
        float*              partp = (float*)(ws + PART_OFF);
        unsigned long long* reg1  = (unsigned long long*)(ws + REG1_OFF);
        unsigned int*       reg2  = (unsigned int*)(ws + REG2_OFF);

        xcast_kernel<<<(NN / 4 + 255) / 256, 256, 0, stream>>>(x, (__half2*)xh);
        hipMemsetAsync(cur2, 0, NB * sizeof(int), stream);
        for (int r = 0; r < NR; ++r) {
            hipMemsetAsync(cur1, 0, NB * sizeof(int), stream);
            p1_kernel<<<NBLK1, 512, 0, stream>>>(ei, ea, ew, eb, reg1, cur1, r * I4_R);
            p2_kernel<<<NB * NB2, 512, 0, stream>>>(xh, reg1, cur1, reg2, cur2);
        }
        reduce_kernel<<<NB * NSPLIT, 1024, 0, stream>>>(reg2, cur2, partp);

        const int hblocks = (NG + 255) / 256;
        head_kernel2<<<hblocks, 256, 0, stream>>>(x, partp, partp + PSTRIDE,
                                                  conv_root, conv_bias,
                                                  W1, b1, W2, b2, W3, b3, out);
    } else {
        hipMemsetAsync(agg, 0, AGG_BYTES, stream);
        edge_kernel<<<2048, 256, 0, stream>>>(x, ei, ea, ew, eb, agg);
        const int hblocks = (NG + 255) / 256;
        head_kernel<<<hblocks, 256, 0, stream>>>(x, agg, conv_root, conv_bias,
                                                 W1, b1, W2, b2, W3, b3, out);
    }
}

// Round 10
// 1159.652 us; speedup vs baseline: 1.0967x; 1.0967x over previous
//
#include <hip/hip_runtime.h>
#include <hip/hip_fp16.h>
#include <math.h>

// Problem constants (match reference)
constexpr int NG  = 100000;          // graphs
constexpr int NPG = 38;              // nodes per graph
constexpr int NN  = NG * NPG;        // 3,800,000 nodes
constexpr long long NE = 60800000LL; // edges

// Binning
constexpr int BIN_SHIFT = 14;                     // 16384 nodes/bin
constexpr int BINW      = 1 << BIN_SHIFT;
constexpr int NB        = (NN + BINW - 1) / BINW; // 232 bins (src and dst)

// P1 sub-rounds (region reuse keeps ws small)
constexpr int NR    = 4;
constexpr int I4_R  = (int)(NE / 4 / NR);         // 3,800,000 int4 per sub-round
constexpr int NBLK1 = 1000;
constexpr int I4_B  = I4_R / NBLK1;               // 3800 int4 per block (exact)
constexpr int CHUNK = 4096;                       // records per sort chunk
constexpr int CH_I4 = CHUNK / 4;                  // 1024 int4 per chunk

// Region capacities (fixed dataset; mean + >=10 sigma)
constexpr int CAPS1 = 68096;    // per src-bin, per sub-round
constexpr int CAPD  = 267264;   // per dst-bin, all edges
constexpr int NB2   = 4;        // P2 blocks per src-bin
constexpr int NSPLIT = 2;       // reduce splits per dst-bin

// Workspace layout (bytes)
constexpr size_t AGG_BYTES  = (size_t)NN * 4;                 // 15,200,000 (fallback path)
constexpr size_t XH_OFF     = AGG_BYTES;
constexpr size_t XH_BYTES   = (size_t)NB * BINW * 2;          // 7,602,176
constexpr size_t CUR1_OFF   = XH_OFF + XH_BYTES;
constexpr size_t CUR2_OFF   = CUR1_OFF + 1024;
constexpr size_t PSTRIDE    = (size_t)NB * BINW;              // 3,801,088 floats
constexpr size_t PART_OFF   = ((CUR2_OFF + 1024 + 255) / 256) * 256;
constexpr size_t PART_BYTES = (size_t)NSPLIT * PSTRIDE * 4;   // 30,408,704
constexpr size_t REG1_OFF   = PART_OFF + PART_BYTES;
constexpr size_t REG1_BYTES = (size_t)NB * CAPS1 * 8;         // 126,386,176
constexpr size_t REG2_OFF   = REG1_OFF + REG1_BYTES;
constexpr size_t REG2_BYTES = (size_t)NB * CAPD * 4;          // 248,020,992
constexpr size_t WS_NEEDED  = REG2_OFF + REG2_BYTES;          // ~407 MiB

// ---------------------------------------------------------------------------
// X cast: f32 -> fp16 copy
// ---------------------------------------------------------------------------
__global__ void __launch_bounds__(256) xcast_kernel(
    const float* __restrict__ x, __half2* __restrict__ xh2)
{
    const int i = blockIdx.x * 256 + threadIdx.x;    // over NN/4
    if (i < NN / 4) {
        float4 v = ((const float4*)x)[i];
        xh2[2 * i + 0] = __floats2half2_rn(v.x, v.y);
        xh2[2 * i + 1] = __floats2half2_rn(v.z, v.w);
    }
}

// ---------------------------------------------------------------------------
// P1 (round-8 proven version): partition edges by SRC-bin.
// Record u64 = [srclow14 | dst22 | fp16(ea*w+b)]. LDS counting sort per
// 4096-record chunk with LDS-atomic ranks; dynamic run allocation on cur1.
// ---------------------------------------------------------------------------
__global__ void __launch_bounds__(512) p1_kernel(
    const int*   __restrict__ ei,
    const float* __restrict__ ea,
    const float* __restrict__ wptr,
    const float* __restrict__ bptr,
    unsigned long long* __restrict__ reg1,
    int* __restrict__ cur1,
    int roff)                          // int4 offset of this sub-round
{
    __shared__ unsigned long long sbuf[CHUNK];   // 32 KB
    __shared__ unsigned char     sbin[CHUNK];    // 4 KB
    __shared__ int s_scan[256];                  // 1 KB
    __shared__ int gofs[NB];

    const int t = threadIdx.x;
    if (t < 256) s_scan[t] = 0;
    __syncthreads();

    const float w = wptr[0], b = bptr[0];
    const int4*   src4 = (const int4*)ei + roff + (size_t)blockIdx.x * I4_B;
    const int4*   dst4 = (const int4*)(ei + NE) + roff + (size_t)blockIdx.x * I4_B;
    const float4* ea4  = (const float4*)ea + roff + (size_t)blockIdx.x * I4_B;

    for (int c0 = 0; c0 < I4_B; c0 += CH_I4) {
        const int n4 = min(CH_I4, I4_B - c0);
        int rbin[8]; unsigned long long rpk[8]; int rpos[8];
        #pragma unroll
        for (int u = 0; u < 2; ++u) {
            const int j = u * 512 + t;
            const bool act = j < n4;
            int4   s4 = make_int4(0, 0, 0, 0);
            int4   d4 = make_int4(0, 0, 0, 0);
            float4 e4 = make_float4(0.f, 0.f, 0.f, 0.f);
            if (act) { s4 = src4[c0 + j]; d4 = dst4[c0 + j]; e4 = ea4[c0 + j]; }
            int   ss[4] = {s4.x, s4.y, s4.z, s4.w};
            int   dd[4] = {d4.x, d4.y, d4.z, d4.w};
            float ee[4] = {e4.x, e4.y, e4.z, e4.w};
            #pragma unroll
            for (int k = 0; k < 4; ++k) {
                const int idx = u * 4 + k;
                if (act) {
                    const int bin = ss[k] >> BIN_SHIFT;
                    __half_raw hr = __float2half_rn(ee[k] * w + b);
                    rbin[idx] = bin;
                    rpk[idx]  = ((unsigned long long)(unsigned)(ss[k] & (BINW - 1)) << 38)
                              | ((unsigned long long)(unsigned)dd[k] << 16)
                              | (unsigned long long)(unsigned short)hr.x;
                    rpos[idx] = atomicAdd(&s_scan[bin], 1);
                } else { rbin[idx] = -1; rpk[idx] = 0; rpos[idx] = 0; }
            }
        }
        __syncthreads();

        // inclusive Hillis-Steele scan over 256 slots
        int acc = 0;
        if (t < 256) acc = s_scan[t];
        for (int off = 1; off < 256; off <<= 1) {
            int tmp = 0;
            if (t < 256 && t >= off) tmp = s_scan[t - off];
            __syncthreads();
            if (t < 256) { acc += tmp; s_scan[t] = acc; }
            __syncthreads();
        }

        // allocate run offsets in global regions
        if (t < NB) {
            const int excl = (t == 0) ? 0 : s_scan[t - 1];
            const int rl   = s_scan[t] - excl;
            gofs[t] = (rl > 0) ? atomicAdd(&cur1[t], rl) : 0;
        }
        // scatter into sorted LDS buffer
        #pragma unroll
        for (int k = 0; k < 8; ++k) {
            if (rbin[k] >= 0) {
                const int excl = (rbin[k] == 0) ? 0 : s_scan[rbin[k] - 1];
                const int idx  = excl + rpos[k];
                sbuf[idx] = rpk[k];
                sbin[idx] = (unsigned char)rbin[k];
            }
        }
        __syncthreads();

        // coalesced run write-out
        const int tot = n4 * 4;
        for (int k = t; k < tot; k += 512) {
            const unsigned long long r = sbuf[k];
            const int bin  = sbin[k];
            const int excl = (bin == 0) ? 0 : s_scan[bin - 1];
            reg1[(size_t)bin * CAPS1 + gofs[bin] + (k - excl)] = r;
        }
        __syncthreads();
        if (t < 256) s_scan[t] = 0;
        __syncthreads();
    }
}

// ---------------------------------------------------------------------------
// P2 (round-8 proven version + new pack): per src-bin, xh slice in LDS;
// msg = xh_lds[srclow] * m; partition by DST-bin into 4B records
// [dstlow14 << 18 | fp16(msg)]  (<<18 so that r>>16 = byte offset in reduce).
// ---------------------------------------------------------------------------
__global__ void __launch_bounds__(512) p2_kernel(
    const __half* __restrict__ xh,
    const unsigned long long* __restrict__ reg1,
    const int* __restrict__ cur1,
    unsigned int* __restrict__ reg2,
    int* __restrict__ cur2)
{
    __shared__ __half        xsl[BINW];    // 32 KB
    __shared__ unsigned int  sbuf[CHUNK];  // 16 KB
    __shared__ unsigned char sbin[CHUNK];  // 4 KB
    __shared__ int s_scan[256];
    __shared__ int gofs[NB];

    const int t  = threadIdx.x;
    const int sb = blockIdx.x >> 2;        // NB2 = 4
    const int jb = blockIdx.x & 3;

    {   // stage xh slice (2048 uint4)
        const uint4* s = (const uint4*)(xh + (size_t)sb * BINW);
        uint4* d = (uint4*)xsl;
        for (int i = t; i < BINW / 8; i += 512) d[i] = s[i];
    }
    if (t < 256) s_scan[t] = 0;
    __syncthreads();

    const int n2    = cur1[sb];
    const int cpb   = (n2 + NB2 - 1) / NB2;
    const int start = jb * cpb;
    const int end   = min(start + cpb, n2);
    const unsigned long long* seg = reg1 + (size_t)sb * CAPS1;

    for (int c0 = start; c0 < end; c0 += CHUNK) {
        const int cnt = min(CHUNK, end - c0);
        int rbin[8]; unsigned int rpk[8]; int rpos[8];
        #pragma unroll
        for (int u = 0; u < 8; ++u) {
            const int j = u * 512 + t;
            if (j < cnt) {
                const unsigned long long r = seg[c0 + j];
                const int srclow        = (int)(r >> 38);
                const unsigned int dst  = (unsigned int)(r >> 16) & 0x3FFFFFu;
                __half_raw hm; hm.x = (unsigned short)(r & 0xFFFFu);
                const float msg = __half2float(xsl[srclow]) * __half2float(__half(hm));
                __half_raw ho = __float2half_rn(msg);
                const int bin = (int)(dst >> BIN_SHIFT);
                rbin[u] = bin;
                rpk[u]  = ((dst & (unsigned)(BINW - 1)) << 18) | (unsigned int)(unsigned short)ho.x;
                rpos[u] = atomicAdd(&s_scan[bin], 1);
            } else { rbin[u] = -1; rpk[u] = 0; rpos[u] = 0; }
        }
        __syncthreads();

        int acc = 0;
        if (t < 256) acc = s_scan[t];
        for (int off = 1; off < 256; off <<= 1) {
            int tmp = 0;
            if (t < 256 && t >= off) tmp = s_scan[t - off];
            __syncthreads();
            if (t < 256) { acc += tmp; s_scan[t] = acc; }
            __syncthreads();
        }

        if (t < NB) {
            const int excl = (t == 0) ? 0 : s_scan[t - 1];
            const int rl   = s_scan[t] - excl;
            gofs[t] = (rl > 0) ? atomicAdd(&cur2[t], rl) : 0;
        }
        #pragma unroll
        for (int u = 0; u < 8; ++u) {
            if (rbin[u] >= 0) {
                const int excl = (rbin[u] == 0) ? 0 : s_scan[rbin[u] - 1];
                const int idx  = excl + rpos[u];
                sbuf[idx] = rpk[u];
                sbin[idx] = (unsigned char)rbin[u];
            }
        }
        __syncthreads();

        for (int k = t; k < cnt; k += 512) {
            const unsigned int r = sbuf[k];
            const int bin  = sbin[k];
            const int excl = (bin == 0) ? 0 : s_scan[bin - 1];
            reg2[(size_t)bin * CAPD + gofs[bin] + (k - excl)] = r;
        }
        __syncthreads();
        if (t < 256) s_scan[t] = 0;
        __syncthreads();
    }
}

// ---------------------------------------------------------------------------
// P3: minimal-instruction reduce. Record r = dstlow<<18 | fp16:
//   byte_off = r >> 16 (= dstlow*4);  val: v_cvt_f32_f16 on low bits (no mask)
//   -> ~2 VALU + 1 DS + 1 load per record.
// ---------------------------------------------------------------------------
__global__ void __launch_bounds__(1024) reduce_kernel(
    const unsigned int* __restrict__ reg2,
    const int* __restrict__ cur2,
    float* __restrict__ part_agg)
{
    __shared__ float acc[BINW];      // 64 KB
    const int t    = threadIdx.x;
    const int b    = blockIdx.x >> 1;
    const int part = blockIdx.x & 1;
    for (int i = t; i < BINW; i += 1024) acc[i] = 0.0f;
    __syncthreads();

    const int n    = cur2[b];
    const int half = n >> 1;
    const int i0   = part ? half : 0;
    const int i1   = part ? n : half;
    const unsigned int* seg = reg2 + (size_t)b * CAPD;
    char* accb = (char*)acc;

    int k = i0 + t;
    for (; k + 7168 < i1; k += 8192) {
        unsigned int r[8];
        #pragma unroll
        for (int u = 0; u < 8; ++u) r[u] = seg[k + u * 1024];
        #pragma unroll
        for (int u = 0; u < 8; ++u) {
            float v;
            asm("v_cvt_f32_f16 %0, %1" : "=v"(v) : "v"(r[u]));
            atomicAdd((float*)(accb + (r[u] >> 16)), v);
        }
    }
    for (; k < i1; k += 1024) {
        unsigned int r = seg[k];
        float v;
        asm("v_cvt_f32_f16 %0, %1" : "=v"(v) : "v"(r));
        atomicAdd((float*)(accb + (r >> 16)), v);
    }
    __syncthreads();

    float* dst = part_agg + (size_t)part * PSTRIDE + ((size_t)b << BIN_SHIFT);
    for (int i = t; i < BINW; i += 1024) dst[i] = acc[i];
}

// ---------------------------------------------------------------------------
// Fallback single-pass edge kernel (used only if ws_size too small)
// ---------------------------------------------------------------------------
__global__ void __launch_bounds__(256) edge_kernel(
    const float* __restrict__ x,
    const int*   __restrict__ ei,
    const float* __restrict__ ea,
    const float* __restrict__ wptr,
    const float* __restrict__ bptr,
    float*       __restrict__ agg)
{
    const float w = wptr[0];
    const float b = bptr[0];
    const int nvec = (int)(NE / 4);
    const int4*   src4 = (const int4*)ei;
    const int4*   dst4 = (const int4*)(ei + NE);
    const float4* ea4  = (const float4*)ea;
    const int stride = gridDim.x * blockDim.x;
    for (int i = blockIdx.x * blockDim.x + threadIdx.x; i < nvec; i += stride) {
        int4   s = src4[i];
        int4   d = dst4[i];
        float4 e = ea4[i];
        atomicAdd(&agg[d.x], x[s.x] * (e.x * w + b));
        atomicAdd(&agg[d.y], x[s.y] * (e.y * w + b));
        atomicAdd(&agg[d.z], x[s.z] * (e.z * w + b));
        atomicAdd(&agg[d.w], x[s.w] * (e.w * w + b));
    }
}

// ---------------------------------------------------------------------------
// Head (main path): nodes = x*cr + (p0+p1) + cb, MLP 38->4->4->1, sigmoid*11
// ---------------------------------------------------------------------------
__global__ void __launch_bounds__(256) head_kernel2(
    const float* __restrict__ x,
    const float* __restrict__ p0,
    const float* __restrict__ p1,
    const float* __restrict__ conv_root,
    const float* __restrict__ conv_bias,
    const float* __restrict__ W1, const float* __restrict__ b1,
    const float* __restrict__ W2, const float* __restrict__ b2,
    const float* __restrict__ W3, const float* __restrict__ b3,
    float* __restrict__ out)
{
    __shared__ float nv[256 * NPG];
    const float cr = conv_root[0];
    const float cb = conv_bias[0];

    const int gbase = blockIdx.x * 256;
    const int gcount = (NG - gbase < 256) ? (NG - gbase) : 256;
    const int fcount = gcount * NPG;
    const long long nbase = (long long)gbase * NPG;

    for (int k = threadIdx.x; k < fcount; k += 256) {
        long long gi = nbase + k;
        nv[k] = x[gi] * cr + p0[gi] + p1[gi] + cb;
    }
    __syncthreads();

    const int g = gbase + threadIdx.x;
    if (g < NG) {
        const float* p = &nv[threadIdx.x * NPG];
        float h0 = b1[0], h1 = b1[1], h2 = b1[2], h3 = b1[3];
        #pragma unroll
        for (int j = 0; j < NPG; ++j) {
            float v = p[j];
            h0 += v * W1[j * 4 + 0];
            h1 += v * W1[j * 4 + 1];
            h2 += v * W1[j * 4 + 2];
            h3 += v * W1[j * 4 + 3];
        }
        h0 = fmaxf(h0, 0.f); h1 = fmaxf(h1, 0.f);
        h2 = fmaxf(h2, 0.f); h3 = fmaxf(h3, 0.f);

        float q0 = b2[0] + h0 * W2[0] + h1 * W2[4] + h2 * W2[8]  + h3 * W2[12];
        float q1 = b2[1] + h0 * W2[1] + h1 * W2[5] + h2 * W2[9]  + h3 * W2[13];
        float q2 = b2[2] + h0 * W2[2] + h1 * W2[6] + h2 * W2[10] + h3 * W2[14];
        float q3 = b2[3] + h0 * W2[3] + h1 * W2[7] + h2 * W2[11] + h3 * W2[15];
        q0 = fmaxf(q0, 0.f); q1 = fmaxf(q1, 0.f);
        q2 = fmaxf(q2, 0.f); q3 = fmaxf(q3, 0.f);

        float z = b3[0] + q0 * W3[0] + q1 * W3[1] + q2 * W3[2] + q3 * W3[3];
        float sgm = 1.0f / (1.0f + __expf(-z));
        out[g] = 11.0f * sgm;
    }
}

// ---------------------------------------------------------------------------
// Head (fallback path): reads agg
// ---------------------------------------------------------------------------
__global__ void __launch_bounds__(256) head_kernel(
    const float* __restrict__ x,
    const float* __restrict__ agg,
    const float* __restrict__ conv_root,
    const float* __restrict__ conv_bias,
    const float* __restrict__ W1, const float* __restrict__ b1,
    const float* __restrict__ W2, const float* __restrict__ b2,
    const float* __restrict__ W3, const float* __restrict__ b3,
    float* __restrict__ out)
{
    __shared__ float nv[256 * NPG];
    const float cr = conv_root[0];
    const float cb = conv_bias[0];

    const int gbase = blockIdx.x * 256;
    const int gcount = (NG - gbase < 256) ? (NG - gbase) : 256;
    const int fcount = gcount * NPG;
    const long long nbase = (long long)gbase * NPG;

    for (int k = threadIdx.x; k < fcount; k += 256) {
        long long gi = nbase + k;
        nv[k] = x[gi] * cr + agg[gi] + cb;
    }
    __syncthreads();

    const int g = gbase + threadIdx.x;
    if (g < NG) {
        const float* p = &nv[threadIdx.x * NPG];
        float h0 = b1[0], h1 = b1[1], h2 = b1[2], h3 = b1[3];
        #pragma unroll
        for (int j = 0; j < NPG; ++j) {
            float v = p[j];
            h0 += v * W1[j * 4 + 0];
            h1 += v * W1[j * 4 + 1];
            h2 += v * W1[j * 4 + 2];
            h3 += v * W1[j * 4 + 3];
        }
        h0 = fmaxf(h0, 0.f); h1 = fmaxf(h1, 0.f);
        h2 = fmaxf(h2, 0.f); h3 = fmaxf(h3, 0.f);

        float q0 = b2[0] + h0 * W2[0] + h1 * W2[4] + h2 * W2[8]  + h3 * W2[12];
        float q1 = b2[1] + h0 * W2[1] + h1 * W2[5] + h2 * W2[9]  + h3 * W2[13];
        float q2 = b2[2] + h0 * W2[2] + h1 * W2[6] + h2 * W2[10] + h3 * W2[14];
        float q3 = b2[3] + h0 * W2[3] + h1 * W2[7] + h2 * W2[11] + h3 * W2[15];
        q0 = fmaxf(q0, 0.f); q1 = fmaxf(q1, 0.f);
        q2 = fmaxf(q2, 0.f); q3 = fmaxf(q3, 0.f);

        float z = b3[0] + q0 * W3[0] + q1 * W3[1] + q2 * W3[2] + q3 * W3[3];
        float sgm = 1.0f / (1.0f + __expf(-z));
        out[g] = 11.0f * sgm;
    }
}

extern "C" void kernel_launch(void* const* d_in, const int* in_sizes, int n_in,
                              void* d_out, int out_size, void* d_ws, size_t ws_size,
                              hipStream_t stream) {
    const float* x         = (const float*)d_in[0];
    const int*   ei        = (const int*)  d_in[1];
    const float* ea        = (const float*)d_in[2];
    const float* conv_root = (const float*)d_in[3];
    const float* conv_bias = (const float*)d_in[4];
    const float* ew        = (const float*)d_in[5];
    const float* eb        = (const float*)d_in[6];
    const float* W1        = (const float*)d_in[7];
    const float* b1        = (const float*)d_in[8];
    const float* W2        = (const float*)d_in[9];
    const float* b2        = (const float*)d_in[10];
    const float* W3        = (const float*)d_in[11];
    const float* b3        = (const float*)d_in[12];

    char*  ws  = (char*)d_ws;
    float* agg = (float*)ws;
    float* out = (float*)d_out;

    if (ws_size >= WS_NEEDED) {
        __half*             xh    = (__half*)(ws + XH_OFF);
        int*                cur1  = (int*)(ws + CUR1_OFF);
        int*                cur2  = (int*)(ws + CUR2_OFF);
        float*              partp = (float*)(ws + PART_OFF);
        unsigned long long* reg1  = (unsigned long long*)(ws + REG1_OFF);
        unsigned int*       reg2  = (unsigned int*)(ws + REG2_OFF);

        xcast_kernel<<<(NN / 4 + 255) / 256, 256, 0, stream>>>(x, (__half2*)xh);
        hipMemsetAsync(cur2, 0, NB * sizeof(int), stream);
        for (int r = 0; r < NR; ++r) {
            hipMemsetAsync(cur1, 0, NB * sizeof(int), stream);
            p1_kernel<<<NBLK1, 512, 0, stream>>>(ei, ea, ew, eb, reg1, cur1, r * I4_R);
            p2_kernel<<<NB * NB2, 512, 0, stream>>>(xh, reg1, cur1, reg2, cur2);
        }
        reduce_kernel<<<NB * NSPLIT, 1024, 0, stream>>>(reg2, cur2, partp);

        const int hblocks = (NG + 255) / 256;
        head_kernel2<<<hblocks, 256, 0, stream>>>(x, partp, partp + PSTRIDE,
                                                  conv_root, conv_bias,
                                                  W1, b1, W2, b2, W3, b3, out);
    } else {
        hipMemsetAsync(agg, 0, AGG_BYTES, stream);
        edge_kernel<<<2048, 256, 0, stream>>>(x, ei, ea, ew, eb, agg);
        const int hblocks = (NG + 255) / 256;
        head_kernel<<<hblocks, 256, 0, stream>>>(x, agg, conv_root, conv_bias,
                                                 W1, b1, W2, b2, W3, b3, out);
    }
}